// Round 7
// baseline (498.882 us; speedup 1.0000x reference)
//
#include <hip/hip_runtime.h>
#include <hip/hip_bf16.h>

#define N_NODES 50000
#define N_EDGES 800000
#define F 256
#define NGRAPH 64
#define NCLS 16
#define NBLK_N 196   // ceil(50000/256)

typedef short short8 __attribute__((ext_vector_type(8)));
typedef float f32x4 __attribute__((ext_vector_type(4)));

__device__ __forceinline__ float bf2f(ushort u) {
    unsigned v = ((unsigned)u) << 16;
    return __uint_as_float(v);
}
__device__ __forceinline__ ushort f2bf(float f) {
    __hip_bfloat16 b = __float2bfloat16(f);   // RNE
    return *reinterpret_cast<ushort*>(&b);
}
__device__ __forceinline__ float bflo(uint u) { return __uint_as_float(u << 16); }
__device__ __forceinline__ float bfhi(uint u) { return __uint_as_float(u & 0xffff0000u); }

// ---------------- CSR build ----------------

__global__ __launch_bounds__(256) void k_zero_int(int* __restrict__ p, int n) {
    int i = blockIdx.x * 256 + threadIdx.x;
    if (i < n) p[i] = 0;
}

__global__ __launch_bounds__(256) void k_count(const int* __restrict__ dst,
                                               int* __restrict__ ecnt) {
    int e = blockIdx.x * 256 + threadIdx.x;
    if (e < N_EDGES) atomicAdd(&ecnt[dst[e]], 1);
}

__global__ __launch_bounds__(256) void k_dinv(const int* __restrict__ ecnt,
                                              float* __restrict__ dinv) {
    int n = blockIdx.x * 256 + threadIdx.x;
    if (n < N_NODES) dinv[n] = rsqrtf((float)(ecnt[n] + 1));  // +1 self-loop
}

__global__ __launch_bounds__(256) void k_scan_block(const int* __restrict__ ecnt,
                                                    int* __restrict__ rowptr,
                                                    int* __restrict__ blkSum) {
    __shared__ int sh[256];
    int i = blockIdx.x * 256 + threadIdx.x;
    int v = (i < N_NODES) ? ecnt[i] : 0;
    sh[threadIdx.x] = v;
    __syncthreads();
#pragma unroll
    for (int off = 1; off < 256; off <<= 1) {
        int t = (threadIdx.x >= off) ? sh[threadIdx.x - off] : 0;
        __syncthreads();
        sh[threadIdx.x] += t;
        __syncthreads();
    }
    if (i < N_NODES) rowptr[i] = sh[threadIdx.x] - v;
    if (threadIdx.x == 255) blkSum[blockIdx.x] = sh[255];
}

__global__ __launch_bounds__(256) void k_scan_tops(int* __restrict__ blkSum,
                                                   int* __restrict__ blkOff) {
    __shared__ int sh[256];
    int v = (threadIdx.x < NBLK_N) ? blkSum[threadIdx.x] : 0;
    sh[threadIdx.x] = v;
    __syncthreads();
#pragma unroll
    for (int off = 1; off < 256; off <<= 1) {
        int t = (threadIdx.x >= off) ? sh[threadIdx.x - off] : 0;
        __syncthreads();
        sh[threadIdx.x] += t;
        __syncthreads();
    }
    if (threadIdx.x < NBLK_N) blkOff[threadIdx.x] = sh[threadIdx.x] - v;
}

__global__ __launch_bounds__(256) void k_scan_add(int* __restrict__ rowptr,
                                                  const int* __restrict__ blkOff,
                                                  int* __restrict__ cursor) {
    int i = blockIdx.x * 256 + threadIdx.x;
    if (i < N_NODES) {
        int r = rowptr[i] + blkOff[blockIdx.x];
        rowptr[i] = r;
        cursor[i] = r;
    }
    if (i == 0) rowptr[N_NODES] = N_EDGES;
}

__global__ __launch_bounds__(256) void k_fill_csr(const int* __restrict__ src,
                                                  const int* __restrict__ dst,
                                                  int* __restrict__ cursor,
                                                  ushort* __restrict__ csr16) {
    int e = blockIdx.x * 256 + threadIdx.x;
    if (e >= N_EDGES) return;
    int s = src[e];
    int d = dst[e];
    int p = atomicAdd(&cursor[d], 1);
    csr16[p] = (ushort)s;
}

// ---------------- casts / packs ----------------

__global__ __launch_bounds__(256) void k_cast_bf16(const float* __restrict__ in,
                                                   ushort* __restrict__ out,
                                                   int n8) {
    int i = blockIdx.x * 256 + threadIdx.x;
    if (i >= n8) return;
    const float4* ip = (const float4*)(in + (size_t)i * 8);
    float4 a = ip[0], b = ip[1];
    short8 v;
    v[0] = (short)f2bf(a.x); v[1] = (short)f2bf(a.y);
    v[2] = (short)f2bf(a.z); v[3] = (short)f2bf(a.w);
    v[4] = (short)f2bf(b.x); v[5] = (short)f2bf(b.y);
    v[6] = (short)f2bf(b.z); v[7] = (short)f2bf(b.w);
    *(short8*)(out + (size_t)i * 8) = v;
}

// pack W[256][256] f32 -> fragment order bf16
__global__ __launch_bounds__(256) void k_wpack(const float* __restrict__ W,
                                               ushort* __restrict__ Wp) {
    int idx = blockIdx.x * 256 + threadIdx.x;
    if (idx >= 16 * 8 * 64) return;
    int lane = idx & 63;
    int ks = (idx >> 6) & 7;
    int ctg = idx >> 9;
    int kbase = ks * 32 + (lane >> 4) * 8;
    int col = ctg * 16 + (lane & 15);
    short8 v;
#pragma unroll
    for (int e = 0; e < 8; ++e)
        v[e] = (short)f2bf(W[(size_t)(kbase + e) * 256 + col]);
    *(short8*)(Wp + (size_t)idx * 8) = v;
}

// ---------------- MFMA GEMM with dinv-prescaled bf16 output ----------------
// C[r][:] = f2bf( dinv[r] * (A[r][:] @ W) )
// Block covers M=256 rows; W frags (this wave's 64-col slice, all K) stay in
// VGPRs across 16 M-subtiles -> W global traffic amortized 4x vs M=64.

__global__ __launch_bounds__(256, 2) void k_mfma256(const ushort* __restrict__ Ab,
                                                    const ushort* __restrict__ Wp,
                                                    const float* __restrict__ dinv,
                                                    ushort* __restrict__ C) {
    const int t = threadIdx.x;
    const int wv = t >> 6;
    const int l = t & 63;
    const int m0 = blockIdx.x * 256;
    const int colbase = wv * 64;
    const int lrow = l & 15;
    const int lk = (l >> 4) * 8;

    // W fragments for this wave's 4 col-tiles, all 8 k-steps
    short8 wf[4][8];
    const short8* wp = (const short8*)Wp;
#pragma unroll
    for (int ct = 0; ct < 4; ++ct)
#pragma unroll
        for (int ks = 0; ks < 8; ++ks)
            wf[ct][ks] = wp[(size_t)(((wv * 4 + ct) * 8 + ks) * 64) + l];

    for (int msub = 0; msub < 16; ++msub) {
        int arow = m0 + msub * 16 + lrow;
        if (arow >= N_NODES) arow = N_NODES - 1;
        const ushort* ap = Ab + (size_t)arow * F + lk;
        short8 af[8];
#pragma unroll
        for (int ks = 0; ks < 8; ++ks)
            af[ks] = *(const short8*)(ap + ks * 32);

        f32x4 acc[4];
#pragma unroll
        for (int ct = 0; ct < 4; ++ct) acc[ct] = (f32x4){0.f, 0.f, 0.f, 0.f};
#pragma unroll
        for (int ks = 0; ks < 8; ++ks)
#pragma unroll
            for (int ct = 0; ct < 4; ++ct)
                acc[ct] = __builtin_amdgcn_mfma_f32_16x16x32_bf16(af[ks], wf[ct][ks], acc[ct], 0, 0, 0);

        int orow0 = m0 + msub * 16 + (l >> 4) * 4;
        float dv[4];
#pragma unroll
        for (int r = 0; r < 4; ++r)
            dv[r] = (orow0 + r < N_NODES) ? dinv[orow0 + r] : 0.f;
#pragma unroll
        for (int ct = 0; ct < 4; ++ct) {
            int ocol = colbase + ct * 16 + (l & 15);
#pragma unroll
            for (int r = 0; r < 4; ++r) {
                int orow = orow0 + r;
                if (orow < N_NODES)
                    C[(size_t)orow * F + ocol] = f2bf(acc[ct][r] * dv[r]);
            }
        }
    }
}

// ---------------- fused gather aggregation, F=256, bf16 in/out ----------------
// H is dinv-prescaled: out_d = act( bias + dinv_d * (sum_{s in N(d)} H[s] + H[d]) )
// MODE 1: relu(agg)   MODE 2: relu(relu(agg) + hc)
// wave per node; lane owns 4 feats (ushort4, 512 B/wave per row read)

template <int MODE>
__global__ __launch_bounds__(256) void k_gather256(const ushort* __restrict__ H,
                                                   const float* __restrict__ bias,
                                                   const float* __restrict__ dinv,
                                                   const int* __restrict__ rowptr,
                                                   const ushort* __restrict__ csr16,
                                                   const ushort* __restrict__ hc,
                                                   ushort* __restrict__ OUT) {
    int gid = blockIdx.x * 256 + threadIdx.x;
    int n = gid >> 6;
    int lane = gid & 63;
    if (n >= N_NODES) return;
    int c = lane * 4;

    float ax = 0.f, ay = 0.f, az = 0.f, aw = 0.f;
    int i = rowptr[n];
    const int end = rowptr[n + 1];
    for (; i + 7 < end; i += 8) {
        int s[8];
#pragma unroll
        for (int j = 0; j < 8; ++j) s[j] = csr16[i + j];
        ushort4 v[8];
#pragma unroll
        for (int j = 0; j < 8; ++j)
            v[j] = *(const ushort4*)(H + (size_t)s[j] * F + c);
#pragma unroll
        for (int j = 0; j < 8; ++j) {
            ax += bf2f(v[j].x); ay += bf2f(v[j].y);
            az += bf2f(v[j].z); aw += bf2f(v[j].w);
        }
    }
    for (; i + 1 < end; i += 2) {
        int s0 = csr16[i], s1 = csr16[i + 1];
        ushort4 v0 = *(const ushort4*)(H + (size_t)s0 * F + c);
        ushort4 v1 = *(const ushort4*)(H + (size_t)s1 * F + c);
        ax += bf2f(v0.x) + bf2f(v1.x); ay += bf2f(v0.y) + bf2f(v1.y);
        az += bf2f(v0.z) + bf2f(v1.z); aw += bf2f(v0.w) + bf2f(v1.w);
    }
    if (i < end) {
        int s0 = csr16[i];
        ushort4 v0 = *(const ushort4*)(H + (size_t)s0 * F + c);
        ax += bf2f(v0.x); ay += bf2f(v0.y); az += bf2f(v0.z); aw += bf2f(v0.w);
    }

    // self-loop + bias + final dinv scale
    const ushort4 h = *(const ushort4*)(H + (size_t)n * F + c);
    const float4 b = *(const float4*)(bias + c);
    float di = dinv[n];
    float sx = b.x + di * (ax + bf2f(h.x));
    float sy = b.y + di * (ay + bf2f(h.y));
    float sz = b.z + di * (az + bf2f(h.z));
    float sw = b.w + di * (aw + bf2f(h.w));

    float ox, oy, oz, ow;
    if (MODE == 1) {
        ox = fmaxf(sx, 0.f); oy = fmaxf(sy, 0.f);
        oz = fmaxf(sz, 0.f); ow = fmaxf(sw, 0.f);
    } else {
        const ushort4 hv = *(const ushort4*)(hc + (size_t)n * F + c);
        ox = fmaxf(fmaxf(sx, 0.f) + bf2f(hv.x), 0.f);
        oy = fmaxf(fmaxf(sy, 0.f) + bf2f(hv.y), 0.f);
        oz = fmaxf(fmaxf(sz, 0.f) + bf2f(hv.z), 0.f);
        ow = fmaxf(fmaxf(sw, 0.f) + bf2f(hv.w), 0.f);
    }
    ushort4 ov;
    ov.x = f2bf(ox); ov.y = f2bf(oy); ov.z = f2bf(oz); ov.w = f2bf(ow);
    *(ushort4*)(OUT + (size_t)n * F + c) = ov;
}

// ---------------- layer 4: GEMM 256 -> 16, dinv-prescaled bf16 out ----------------

__global__ __launch_bounds__(256) void k_gemm16(const ushort* __restrict__ A,
                                                const float* __restrict__ W4,
                                                const float* __restrict__ dinv,
                                                ushort* __restrict__ C) {
    __shared__ float Ws[256][16];
    const int t = threadIdx.x;
    {
        const float4* wp = (const float4*)(W4 + (size_t)t * 16);
        float4 a = wp[0], b = wp[1], c = wp[2], d = wp[3];
        float4* sp = (float4*)&Ws[t][0];
        sp[0] = a; sp[1] = b; sp[2] = c; sp[3] = d;
    }
    __syncthreads();
    int row = blockIdx.x * 256 + t;
    if (row >= N_NODES) return;
    const short8* ap = (const short8*)(A + (size_t)row * F);
    float acc[16];
#pragma unroll
    for (int c = 0; c < 16; ++c) acc[c] = 0.f;
    for (int k8 = 0; k8 < 32; ++k8) {
        short8 a8 = ap[k8];
#pragma unroll
        for (int j = 0; j < 8; ++j) {
            float av = bf2f((ushort)a8[j]);
            const float4* wr = (const float4*)&Ws[k8 * 8 + j][0];
            float4 w0 = wr[0], w1 = wr[1], w2 = wr[2], w3 = wr[3];
            acc[0]  += av * w0.x; acc[1]  += av * w0.y;
            acc[2]  += av * w0.z; acc[3]  += av * w0.w;
            acc[4]  += av * w1.x; acc[5]  += av * w1.y;
            acc[6]  += av * w1.z; acc[7]  += av * w1.w;
            acc[8]  += av * w2.x; acc[9]  += av * w2.y;
            acc[10] += av * w2.z; acc[11] += av * w2.w;
            acc[12] += av * w3.x; acc[13] += av * w3.y;
            acc[14] += av * w3.z; acc[15] += av * w3.w;
        }
    }
    float dv = dinv[row];
    short8 o0, o1;
#pragma unroll
    for (int c = 0; c < 8; ++c) o0[c] = (short)f2bf(acc[c] * dv);
#pragma unroll
    for (int c = 0; c < 8; ++c) o1[c] = (short)f2bf(acc[8 + c] * dv);
    short8* op = (short8*)(C + (size_t)row * 16);
    op[0] = o0; op[1] = o1;
}

// gather for F=16 (prescaled bf16 table; 1.6 MB -> L2-resident)
__global__ __launch_bounds__(256) void k_gather16(const ushort* __restrict__ G16,
                                                  const float* __restrict__ bias,
                                                  const float* __restrict__ dinv,
                                                  const int* __restrict__ rowptr,
                                                  const ushort* __restrict__ csr16,
                                                  float* __restrict__ OUT) {
    int gid = blockIdx.x * 256 + threadIdx.x;
    int n = gid >> 2;
    int q = (gid & 3) * 4;
    if (n >= N_NODES) return;

    float ax = 0.f, ay = 0.f, az = 0.f, aw = 0.f;
    const int end = rowptr[n + 1];
    for (int i = rowptr[n]; i < end; ++i) {
        int s0 = csr16[i];
        const uint2 u = *(const uint2*)(G16 + (size_t)s0 * 16 + q);
        ax += bflo(u.x); ay += bfhi(u.x);
        az += bflo(u.y); aw += bfhi(u.y);
    }
    const uint2 hu = *(const uint2*)(G16 + (size_t)n * 16 + q);
    const float4 b = *(const float4*)(bias + q);
    float di = dinv[n];
    float4 o;
    o.x = b.x + di * (ax + bflo(hu.x));
    o.y = b.y + di * (ay + bfhi(hu.x));
    o.z = b.z + di * (az + bflo(hu.y));
    o.w = b.w + di * (aw + bfhi(hu.y));
    *(float4*)(OUT + (size_t)n * 16 + q) = o;
}

// ---------------- mean pool ----------------

__global__ __launch_bounds__(256) void k_pool_zero(float* __restrict__ pool,
                                                   float* __restrict__ cnt) {
    int i = blockIdx.x * 256 + threadIdx.x;
    if (i < NGRAPH * NCLS) pool[i] = 0.f;
    if (i < NGRAPH) cnt[i] = 0.f;
}

__global__ __launch_bounds__(256) void k_pool(const float* __restrict__ H4,
                                              const int* __restrict__ batch,
                                              float* __restrict__ pool,
                                              float* __restrict__ cnt) {
    __shared__ float ps[NGRAPH][NCLS];
    __shared__ float pc[NGRAPH];
    for (int i = threadIdx.x; i < NGRAPH * NCLS; i += 256) ((float*)ps)[i] = 0.f;
    if (threadIdx.x < NGRAPH) pc[threadIdx.x] = 0.f;
    __syncthreads();
    int n = blockIdx.x * 256 + threadIdx.x;
    if (n < N_NODES) {
        int g = batch[n];
        const float4* hp = (const float4*)(H4 + (size_t)n * 16);
        float4 a = hp[0], b = hp[1], c = hp[2], d = hp[3];
        atomicAdd(&ps[g][0],  a.x); atomicAdd(&ps[g][1],  a.y);
        atomicAdd(&ps[g][2],  a.z); atomicAdd(&ps[g][3],  a.w);
        atomicAdd(&ps[g][4],  b.x); atomicAdd(&ps[g][5],  b.y);
        atomicAdd(&ps[g][6],  b.z); atomicAdd(&ps[g][7],  b.w);
        atomicAdd(&ps[g][8],  c.x); atomicAdd(&ps[g][9],  c.y);
        atomicAdd(&ps[g][10], c.z); atomicAdd(&ps[g][11], c.w);
        atomicAdd(&ps[g][12], d.x); atomicAdd(&ps[g][13], d.y);
        atomicAdd(&ps[g][14], d.z); atomicAdd(&ps[g][15], d.w);
        atomicAdd(&pc[g], 1.f);
    }
    __syncthreads();
    for (int i = threadIdx.x; i < NGRAPH * NCLS; i += 256)
        unsafeAtomicAdd(&pool[i], ((float*)ps)[i]);
    if (threadIdx.x < NGRAPH) unsafeAtomicAdd(&cnt[threadIdx.x], pc[threadIdx.x]);
}

__global__ __launch_bounds__(256) void k_final(const float* __restrict__ pool,
                                               const float* __restrict__ cnt,
                                               float* __restrict__ out) {
    int i = blockIdx.x * 256 + threadIdx.x;
    if (i < NGRAPH * NCLS) out[i] = pool[i] / fmaxf(cnt[i >> 4], 1.f);
}

// ---------------- host ----------------

extern "C" void kernel_launch(void* const* d_in, const int* in_sizes, int n_in,
                              void* d_out, int out_size, void* d_ws, size_t ws_size,
                              hipStream_t stream) {
    const float* x   = (const float*)d_in[0];
    const int*   ei  = (const int*)d_in[1];
    const int*   bvec= (const int*)d_in[2];
    const float* W1  = (const float*)d_in[3];
    const float* b1  = (const float*)d_in[4];
    const float* W2  = (const float*)d_in[5];
    const float* b2  = (const float*)d_in[6];
    const float* W3  = (const float*)d_in[7];
    const float* b3  = (const float*)d_in[8];
    const float* W4  = (const float*)d_in[9];
    const float* b4  = (const float*)d_in[10];
    float* out = (float*)d_out;

    const int* src = ei;
    const int* dst = ei + N_EDGES;

    const size_t NF = (size_t)N_NODES * F;            // 12.8M elems
    float* ws = (float*)d_ws;
    ushort* XA = (ushort*)ws;                          // NF bf16
    ushort* XB = XA + NF;                              // NF bf16
    ushort* Hg = XB + NF;                              // NF bf16 (prescaled GEMM out)
    ushort* G16 = (ushort*)(ws + 3 * NF / 2);          // N*16 bf16 (prescaled)
    float*  H4  = ws + 3 * NF / 2 + 400000;            // N*16 f32
    float*  aux = H4 + (size_t)N_NODES * 16;
    int*    ecnt   = (int*)aux;                        // N
    float*  dinv   = aux + N_NODES;                    // N
    int*    rowptr = (int*)(aux + 2 * N_NODES);        // N+1 (+pad)
    int*    cursor = (int*)(aux + 3 * N_NODES + 64);   // N
    int*    blkSum = (int*)(aux + 4 * N_NODES + 64);   // 256
    int*    blkOff = blkSum + 256;                     // 256
    ushort* csr16  = (ushort*)(blkOff + 256);          // E ushorts
    float*  pool   = (float*)(csr16 + N_EDGES);        // 1024
    float*  cnt    = pool + NGRAPH * NCLS;             // 64
    ushort* Wp1    = (ushort*)(cnt + NGRAPH);          // 65536 each
    ushort* Wp2    = Wp1 + 65536;
    ushort* Wp3    = Wp2 + 65536;

    const int BN = NBLK_N;                        // 196
    const int BE = (N_EDGES + 255) / 256;         // 3125
    const int BM = (N_NODES + 255) / 256;         // 196 MFMA blocks (M=256)
    const int BG = (N_NODES * 64 + 255) / 256;    // 12500 (wave/node)
    const int BC = (int)((NF / 8 + 255) / 256);   // cast blocks

    // ---- CSR build + dinv (needed by GEMM prescale)
    k_zero_int<<<BN, 256, 0, stream>>>(ecnt, N_NODES);
    k_count<<<BE, 256, 0, stream>>>(dst, ecnt);
    k_dinv<<<BN, 256, 0, stream>>>(ecnt, dinv);
    k_scan_block<<<BN, 256, 0, stream>>>(ecnt, rowptr, blkSum);
    k_scan_tops<<<1, 256, 0, stream>>>(blkSum, blkOff);
    k_scan_add<<<BN, 256, 0, stream>>>(rowptr, blkOff, cursor);
    k_fill_csr<<<BE, 256, 0, stream>>>(src, dst, cursor, csr16);

    // ---- casts & weight packs
    k_cast_bf16<<<BC, 256, 0, stream>>>(x, XA, (int)(NF / 8));
    k_wpack<<<32, 256, 0, stream>>>(W1, Wp1);
    k_wpack<<<32, 256, 0, stream>>>(W2, Wp2);
    k_wpack<<<32, 256, 0, stream>>>(W3, Wp3);

    // ---- layer 1: Hg = dinv*(XA@W1); XB = relu(agg(Hg))
    k_mfma256<<<BM, 256, 0, stream>>>(XA, Wp1, dinv, Hg);
    k_gather256<1><<<BG, 256, 0, stream>>>(Hg, b1, dinv, rowptr, csr16, nullptr, XB);

    // ---- layer 2: Hg = dinv*(XB@W2); XA = relu(relu(agg(Hg)) + XB)
    k_mfma256<<<BM, 256, 0, stream>>>(XB, Wp2, dinv, Hg);
    k_gather256<2><<<BG, 256, 0, stream>>>(Hg, b2, dinv, rowptr, csr16, XB, XA);

    // ---- layer 3: Hg = dinv*(XA@W3); XB = relu(relu(agg(Hg)) + XA)
    k_mfma256<<<BM, 256, 0, stream>>>(XA, Wp3, dinv, Hg);
    k_gather256<2><<<BG, 256, 0, stream>>>(Hg, b3, dinv, rowptr, csr16, XA, XB);

    // ---- layer 4: G16 = dinv*(XB@W4); H4 = agg16(G16)
    k_gemm16<<<BN, 256, 0, stream>>>(XB, W4, dinv, G16);
    k_gather16<<<(N_NODES * 4 + 255) / 256, 256, 0, stream>>>(G16, b4, dinv, rowptr, csr16, H4);

    // ---- mean pool
    k_pool_zero<<<5, 256, 0, stream>>>(pool, cnt);
    k_pool<<<BN, 256, 0, stream>>>(H4, bvec, pool, cnt);
    k_final<<<4, 256, 0, stream>>>(pool, cnt, out);
}

// Round 8
// 486.761 us; speedup vs baseline: 1.0249x; 1.0249x over previous
//
#include <hip/hip_runtime.h>
#include <hip/hip_bf16.h>

#define N_NODES 50000
#define N_EDGES 800000
#define F 256
#define NGRAPH 64
#define NCLS 16
#define NBLK_N 196   // ceil(50000/256)

typedef short short8 __attribute__((ext_vector_type(8)));
typedef float f32x4 __attribute__((ext_vector_type(4)));

__device__ __forceinline__ float bf2f(ushort u) {
    unsigned v = ((unsigned)u) << 16;
    return __uint_as_float(v);
}
__device__ __forceinline__ ushort f2bf(float f) {
    __hip_bfloat16 b = __float2bfloat16(f);   // RNE
    return *reinterpret_cast<ushort*>(&b);
}
__device__ __forceinline__ float bflo(uint u) { return __uint_as_float(u << 16); }
__device__ __forceinline__ float bfhi(uint u) { return __uint_as_float(u & 0xffff0000u); }

// ---------------- CSR build ----------------

__global__ __launch_bounds__(256) void k_zero_int(int* __restrict__ p, int n) {
    int i = blockIdx.x * 256 + threadIdx.x;
    if (i < n) p[i] = 0;
}

__global__ __launch_bounds__(256) void k_count(const int* __restrict__ dst,
                                               int* __restrict__ ecnt) {
    int e = blockIdx.x * 256 + threadIdx.x;
    if (e < N_EDGES) atomicAdd(&ecnt[dst[e]], 1);
}

// block-scan over ecnt; also emits dinv (fused, saves a launch)
__global__ __launch_bounds__(256) void k_scan_block(const int* __restrict__ ecnt,
                                                    int* __restrict__ rowptr,
                                                    int* __restrict__ blkSum,
                                                    float* __restrict__ dinv) {
    __shared__ int sh[256];
    int i = blockIdx.x * 256 + threadIdx.x;
    int v = (i < N_NODES) ? ecnt[i] : 0;
    sh[threadIdx.x] = v;
    __syncthreads();
#pragma unroll
    for (int off = 1; off < 256; off <<= 1) {
        int t = (threadIdx.x >= off) ? sh[threadIdx.x - off] : 0;
        __syncthreads();
        sh[threadIdx.x] += t;
        __syncthreads();
    }
    if (i < N_NODES) {
        rowptr[i] = sh[threadIdx.x] - v;
        dinv[i] = rsqrtf((float)(v + 1));   // +1 self-loop
    }
    if (threadIdx.x == 255) blkSum[blockIdx.x] = sh[255];
}

__global__ __launch_bounds__(256) void k_scan_tops(int* __restrict__ blkSum,
                                                   int* __restrict__ blkOff) {
    __shared__ int sh[256];
    int v = (threadIdx.x < NBLK_N) ? blkSum[threadIdx.x] : 0;
    sh[threadIdx.x] = v;
    __syncthreads();
#pragma unroll
    for (int off = 1; off < 256; off <<= 1) {
        int t = (threadIdx.x >= off) ? sh[threadIdx.x - off] : 0;
        __syncthreads();
        sh[threadIdx.x] += t;
        __syncthreads();
    }
    if (threadIdx.x < NBLK_N) blkOff[threadIdx.x] = sh[threadIdx.x] - v;
}

__global__ __launch_bounds__(256) void k_scan_add(int* __restrict__ rowptr,
                                                  const int* __restrict__ blkOff,
                                                  int* __restrict__ cursor) {
    int i = blockIdx.x * 256 + threadIdx.x;
    if (i < N_NODES) {
        int r = rowptr[i] + blkOff[blockIdx.x];
        rowptr[i] = r;
        cursor[i] = r;
    }
    if (i == 0) rowptr[N_NODES] = N_EDGES;
}

__global__ __launch_bounds__(256) void k_fill_csr(const int* __restrict__ src,
                                                  const int* __restrict__ dst,
                                                  int* __restrict__ cursor,
                                                  ushort* __restrict__ csr16) {
    int e = blockIdx.x * 256 + threadIdx.x;
    if (e >= N_EDGES) return;
    int s = src[e];
    int d = dst[e];
    int p = atomicAdd(&cursor[d], 1);
    csr16[p] = (ushort)s;
}

// ---------------- casts / packs ----------------

__global__ __launch_bounds__(256) void k_cast_bf16(const float* __restrict__ in,
                                                   ushort* __restrict__ out,
                                                   int n8) {
    int i = blockIdx.x * 256 + threadIdx.x;
    if (i >= n8) return;
    const float4* ip = (const float4*)(in + (size_t)i * 8);
    float4 a = ip[0], b = ip[1];
    short8 v;
    v[0] = (short)f2bf(a.x); v[1] = (short)f2bf(a.y);
    v[2] = (short)f2bf(a.z); v[3] = (short)f2bf(a.w);
    v[4] = (short)f2bf(b.x); v[5] = (short)f2bf(b.y);
    v[6] = (short)f2bf(b.z); v[7] = (short)f2bf(b.w);
    *(short8*)(out + (size_t)i * 8) = v;
}

// pack W[256][256] f32 -> fragment order bf16
__global__ __launch_bounds__(256) void k_wpack(const float* __restrict__ W,
                                               ushort* __restrict__ Wp) {
    int idx = blockIdx.x * 256 + threadIdx.x;
    if (idx >= 16 * 8 * 64) return;
    int lane = idx & 63;
    int ks = (idx >> 6) & 7;
    int ctg = idx >> 9;
    int kbase = ks * 32 + (lane >> 4) * 8;
    int col = ctg * 16 + (lane & 15);
    short8 v;
#pragma unroll
    for (int e = 0; e < 8; ++e)
        v[e] = (short)f2bf(W[(size_t)(kbase + e) * 256 + col]);
    *(short8*)(Wp + (size_t)idx * 8) = v;
}

// ---------------- MFMA GEMM with dinv-prescaled bf16 output ----------------
// C[r][:] = f2bf( dinv[r] * (A[r][:] @ W) ).  BM=64, 782 blocks.
// W frags split in two ct-pairs (wf[2][8] = 64 VGPR) to cut register
// pressure -> 3 waves/SIMD (launch_bounds 256,3). W refetch is L2-hot.

__global__ __launch_bounds__(256, 3) void k_mfma256(const ushort* __restrict__ Ab,
                                                    const ushort* __restrict__ Wp,
                                                    const float* __restrict__ dinv,
                                                    ushort* __restrict__ C) {
    const int t = threadIdx.x;
    const int wv = t >> 6;
    const int l = t & 63;
    const int m0 = blockIdx.x * 64;
    const int lrow = l & 15;
    const int lk = (l >> 4) * 8;
    const short8* wp = (const short8*)Wp;

#pragma unroll
    for (int cp = 0; cp < 2; ++cp) {
        short8 wf[2][8];
#pragma unroll
        for (int c2 = 0; c2 < 2; ++c2)
#pragma unroll
            for (int ks = 0; ks < 8; ++ks)
                wf[c2][ks] = wp[(size_t)(((wv * 4 + cp * 2 + c2) * 8 + ks) * 64) + l];

#pragma unroll
        for (int msub = 0; msub < 4; ++msub) {
            int arow = m0 + msub * 16 + lrow;
            if (arow >= N_NODES) arow = N_NODES - 1;
            const ushort* ap = Ab + (size_t)arow * F + lk;
            short8 af[8];
#pragma unroll
            for (int ks = 0; ks < 8; ++ks)
                af[ks] = *(const short8*)(ap + ks * 32);

            f32x4 acc[2];
#pragma unroll
            for (int c2 = 0; c2 < 2; ++c2) acc[c2] = (f32x4){0.f, 0.f, 0.f, 0.f};
#pragma unroll
            for (int ks = 0; ks < 8; ++ks)
#pragma unroll
                for (int c2 = 0; c2 < 2; ++c2)
                    acc[c2] = __builtin_amdgcn_mfma_f32_16x16x32_bf16(af[ks], wf[c2][ks], acc[c2], 0, 0, 0);

            int orow0 = m0 + msub * 16 + (l >> 4) * 4;
            float dv[4];
#pragma unroll
            for (int r = 0; r < 4; ++r)
                dv[r] = (orow0 + r < N_NODES) ? dinv[orow0 + r] : 0.f;
#pragma unroll
            for (int c2 = 0; c2 < 2; ++c2) {
                int ocol = wv * 64 + (cp * 2 + c2) * 16 + (l & 15);
#pragma unroll
                for (int r = 0; r < 4; ++r) {
                    int orow = orow0 + r;
                    if (orow < N_NODES)
                        C[(size_t)orow * F + ocol] = f2bf(acc[c2][r] * dv[r]);
                }
            }
        }
    }
}

// ---------------- fused gather aggregation, F=256, bf16 in/out ----------------
// H is dinv-prescaled: out_d = act( bias + dinv_d * (sum_{s in N(d)} H[s] + H[d]) )
// MODE 1: relu(agg)   MODE 2: relu(relu(agg) + hc)

template <int MODE>
__global__ __launch_bounds__(256) void k_gather256(const ushort* __restrict__ H,
                                                   const float* __restrict__ bias,
                                                   const float* __restrict__ dinv,
                                                   const int* __restrict__ rowptr,
                                                   const ushort* __restrict__ csr16,
                                                   const ushort* __restrict__ hc,
                                                   ushort* __restrict__ OUT) {
    int gid = blockIdx.x * 256 + threadIdx.x;
    int n = gid >> 6;
    int lane = gid & 63;
    if (n >= N_NODES) return;
    int c = lane * 4;

    float ax = 0.f, ay = 0.f, az = 0.f, aw = 0.f;
    int i = rowptr[n];
    const int end = rowptr[n + 1];
    for (; i + 7 < end; i += 8) {
        int s[8];
#pragma unroll
        for (int j = 0; j < 8; ++j) s[j] = csr16[i + j];
        ushort4 v[8];
#pragma unroll
        for (int j = 0; j < 8; ++j)
            v[j] = *(const ushort4*)(H + (size_t)s[j] * F + c);
#pragma unroll
        for (int j = 0; j < 8; ++j) {
            ax += bf2f(v[j].x); ay += bf2f(v[j].y);
            az += bf2f(v[j].z); aw += bf2f(v[j].w);
        }
    }
    for (; i + 1 < end; i += 2) {
        int s0 = csr16[i], s1 = csr16[i + 1];
        ushort4 v0 = *(const ushort4*)(H + (size_t)s0 * F + c);
        ushort4 v1 = *(const ushort4*)(H + (size_t)s1 * F + c);
        ax += bf2f(v0.x) + bf2f(v1.x); ay += bf2f(v0.y) + bf2f(v1.y);
        az += bf2f(v0.z) + bf2f(v1.z); aw += bf2f(v0.w) + bf2f(v1.w);
    }
    if (i < end) {
        int s0 = csr16[i];
        ushort4 v0 = *(const ushort4*)(H + (size_t)s0 * F + c);
        ax += bf2f(v0.x); ay += bf2f(v0.y); az += bf2f(v0.z); aw += bf2f(v0.w);
    }

    const ushort4 h = *(const ushort4*)(H + (size_t)n * F + c);
    const float4 b = *(const float4*)(bias + c);
    float di = dinv[n];
    float sx = b.x + di * (ax + bf2f(h.x));
    float sy = b.y + di * (ay + bf2f(h.y));
    float sz = b.z + di * (az + bf2f(h.z));
    float sw = b.w + di * (aw + bf2f(h.w));

    float ox, oy, oz, ow;
    if (MODE == 1) {
        ox = fmaxf(sx, 0.f); oy = fmaxf(sy, 0.f);
        oz = fmaxf(sz, 0.f); ow = fmaxf(sw, 0.f);
    } else {
        const ushort4 hv = *(const ushort4*)(hc + (size_t)n * F + c);
        ox = fmaxf(fmaxf(sx, 0.f) + bf2f(hv.x), 0.f);
        oy = fmaxf(fmaxf(sy, 0.f) + bf2f(hv.y), 0.f);
        oz = fmaxf(fmaxf(sz, 0.f) + bf2f(hv.z), 0.f);
        ow = fmaxf(fmaxf(sw, 0.f) + bf2f(hv.w), 0.f);
    }
    ushort4 ov;
    ov.x = f2bf(ox); ov.y = f2bf(oy); ov.z = f2bf(oz); ov.w = f2bf(ow);
    *(ushort4*)(OUT + (size_t)n * F + c) = ov;
}

// ---------------- layer 4: GEMM 256 -> 16, dinv-prescaled bf16 out ----------------

__global__ __launch_bounds__(256) void k_gemm16(const ushort* __restrict__ A,
                                                const float* __restrict__ W4,
                                                const float* __restrict__ dinv,
                                                ushort* __restrict__ C) {
    __shared__ float Ws[256][16];
    const int t = threadIdx.x;
    {
        const float4* wp = (const float4*)(W4 + (size_t)t * 16);
        float4 a = wp[0], b = wp[1], c = wp[2], d = wp[3];
        float4* sp = (float4*)&Ws[t][0];
        sp[0] = a; sp[1] = b; sp[2] = c; sp[3] = d;
    }
    __syncthreads();
    int row = blockIdx.x * 256 + t;
    if (row >= N_NODES) return;
    const short8* ap = (const short8*)(A + (size_t)row * F);
    float acc[16];
#pragma unroll
    for (int c = 0; c < 16; ++c) acc[c] = 0.f;
    for (int k8 = 0; k8 < 32; ++k8) {
        short8 a8 = ap[k8];
#pragma unroll
        for (int j = 0; j < 8; ++j) {
            float av = bf2f((ushort)a8[j]);
            const float4* wr = (const float4*)&Ws[k8 * 8 + j][0];
            float4 w0 = wr[0], w1 = wr[1], w2 = wr[2], w3 = wr[3];
            acc[0]  += av * w0.x; acc[1]  += av * w0.y;
            acc[2]  += av * w0.z; acc[3]  += av * w0.w;
            acc[4]  += av * w1.x; acc[5]  += av * w1.y;
            acc[6]  += av * w1.z; acc[7]  += av * w1.w;
            acc[8]  += av * w2.x; acc[9]  += av * w2.y;
            acc[10] += av * w2.z; acc[11] += av * w2.w;
            acc[12] += av * w3.x; acc[13] += av * w3.y;
            acc[14] += av * w3.z; acc[15] += av * w3.w;
        }
    }
    float dv = dinv[row];
    short8 o0, o1;
#pragma unroll
    for (int c = 0; c < 8; ++c) o0[c] = (short)f2bf(acc[c] * dv);
#pragma unroll
    for (int c = 0; c < 8; ++c) o1[c] = (short)f2bf(acc[8 + c] * dv);
    short8* op = (short8*)(C + (size_t)row * 16);
    op[0] = o0; op[1] = o1;
}

// ---------------- fused layer-4 gather + mean-pool accumulate ----------------
// thread = (node, quarter). agg into f32, then LDS per-graph accumulate
// (batch_vec sorted -> few graphs per block -> few global atomics).

__global__ __launch_bounds__(256) void k_g16pool(const ushort* __restrict__ G16,
                                                 const float* __restrict__ bias,
                                                 const float* __restrict__ dinv,
                                                 const int* __restrict__ rowptr,
                                                 const ushort* __restrict__ csr16,
                                                 const int* __restrict__ batch,
                                                 float* __restrict__ pool,
                                                 float* __restrict__ cnt) {
    __shared__ float ps[NGRAPH][NCLS];
    __shared__ float pc[NGRAPH];
    for (int i = threadIdx.x; i < NGRAPH * NCLS; i += 256) ((float*)ps)[i] = 0.f;
    if (threadIdx.x < NGRAPH) pc[threadIdx.x] = 0.f;
    __syncthreads();

    int gid = blockIdx.x * 256 + threadIdx.x;
    int n = gid >> 2;
    int q = (gid & 3) * 4;
    if (n < N_NODES) {
        float ax = 0.f, ay = 0.f, az = 0.f, aw = 0.f;
        const int end = rowptr[n + 1];
        for (int i = rowptr[n]; i < end; ++i) {
            int s0 = csr16[i];
            const uint2 u = *(const uint2*)(G16 + (size_t)s0 * 16 + q);
            ax += bflo(u.x); ay += bfhi(u.x);
            az += bflo(u.y); aw += bfhi(u.y);
        }
        const uint2 hu = *(const uint2*)(G16 + (size_t)n * 16 + q);
        const float4 b = *(const float4*)(bias + q);
        float di = dinv[n];
        int g = batch[n];
        atomicAdd(&ps[g][q + 0], b.x + di * (ax + bflo(hu.x)));
        atomicAdd(&ps[g][q + 1], b.y + di * (ay + bfhi(hu.x)));
        atomicAdd(&ps[g][q + 2], b.z + di * (az + bflo(hu.y)));
        atomicAdd(&ps[g][q + 3], b.w + di * (aw + bfhi(hu.y)));
        if ((gid & 3) == 0) atomicAdd(&pc[g], 1.f);
    }
    __syncthreads();

    for (int i = threadIdx.x; i < NGRAPH * NCLS; i += 256) {
        float v = ((float*)ps)[i];
        if (v != 0.f) unsafeAtomicAdd(&pool[i], v);
    }
    if (threadIdx.x < NGRAPH) {
        float v = pc[threadIdx.x];
        if (v > 0.f) unsafeAtomicAdd(&cnt[threadIdx.x], v);
    }
}

__global__ __launch_bounds__(256) void k_pool_zero(float* __restrict__ pool,
                                                   float* __restrict__ cnt) {
    int i = blockIdx.x * 256 + threadIdx.x;
    if (i < NGRAPH * NCLS) pool[i] = 0.f;
    if (i < NGRAPH) cnt[i] = 0.f;
}

__global__ __launch_bounds__(256) void k_final(const float* __restrict__ pool,
                                               const float* __restrict__ cnt,
                                               float* __restrict__ out) {
    int i = blockIdx.x * 256 + threadIdx.x;
    if (i < NGRAPH * NCLS) out[i] = pool[i] / fmaxf(cnt[i >> 4], 1.f);
}

// ---------------- host ----------------

extern "C" void kernel_launch(void* const* d_in, const int* in_sizes, int n_in,
                              void* d_out, int out_size, void* d_ws, size_t ws_size,
                              hipStream_t stream) {
    const float* x   = (const float*)d_in[0];
    const int*   ei  = (const int*)d_in[1];
    const int*   bvec= (const int*)d_in[2];
    const float* W1  = (const float*)d_in[3];
    const float* b1  = (const float*)d_in[4];
    const float* W2  = (const float*)d_in[5];
    const float* b2  = (const float*)d_in[6];
    const float* W3  = (const float*)d_in[7];
    const float* b3  = (const float*)d_in[8];
    const float* W4  = (const float*)d_in[9];
    const float* b4  = (const float*)d_in[10];
    float* out = (float*)d_out;

    const int* src = ei;
    const int* dst = ei + N_EDGES;

    const size_t NF = (size_t)N_NODES * F;            // 12.8M elems
    float* ws = (float*)d_ws;
    ushort* XA = (ushort*)ws;                          // NF bf16
    ushort* XB = XA + NF;                              // NF bf16
    ushort* Hg = XB + NF;                              // NF bf16 (prescaled GEMM out)
    ushort* G16 = (ushort*)(ws + 3 * NF / 2);          // N*16 bf16 (prescaled)
    float*  aux = ws + 3 * NF / 2 + 400000;
    int*    ecnt   = (int*)aux;                        // N
    float*  dinv   = aux + N_NODES;                    // N
    int*    rowptr = (int*)(aux + 2 * N_NODES);        // N+1 (+pad)
    int*    cursor = (int*)(aux + 3 * N_NODES + 64);   // N
    int*    blkSum = (int*)(aux + 4 * N_NODES + 64);   // 256
    int*    blkOff = blkSum + 256;                     // 256
    ushort* csr16  = (ushort*)(blkOff + 256);          // E ushorts
    float*  pool   = (float*)(csr16 + N_EDGES);        // 1024
    float*  cnt    = pool + NGRAPH * NCLS;             // 64
    ushort* Wp1    = (ushort*)(cnt + NGRAPH);          // 65536 each
    ushort* Wp2    = Wp1 + 65536;
    ushort* Wp3    = Wp2 + 65536;

    const int BN = NBLK_N;                        // 196
    const int BE = (N_EDGES + 255) / 256;         // 3125
    const int BM = (N_NODES + 63) / 64;           // 782 MFMA blocks (BM=64)
    const int BG = (N_NODES * 64 + 255) / 256;    // 12500 (wave/node)
    const int B4 = (N_NODES * 4 + 255) / 256;     // 782 (thread per node-quarter)
    const int BC = (int)((NF / 8 + 255) / 256);   // cast blocks

    // ---- CSR build + dinv
    k_zero_int<<<BN, 256, 0, stream>>>(ecnt, N_NODES);
    k_pool_zero<<<5, 256, 0, stream>>>(pool, cnt);
    k_count<<<BE, 256, 0, stream>>>(dst, ecnt);
    k_scan_block<<<BN, 256, 0, stream>>>(ecnt, rowptr, blkSum, dinv);
    k_scan_tops<<<1, 256, 0, stream>>>(blkSum, blkOff);
    k_scan_add<<<BN, 256, 0, stream>>>(rowptr, blkOff, cursor);
    k_fill_csr<<<BE, 256, 0, stream>>>(src, dst, cursor, csr16);

    // ---- casts & weight packs
    k_cast_bf16<<<BC, 256, 0, stream>>>(x, XA, (int)(NF / 8));
    k_wpack<<<32, 256, 0, stream>>>(W1, Wp1);
    k_wpack<<<32, 256, 0, stream>>>(W2, Wp2);
    k_wpack<<<32, 256, 0, stream>>>(W3, Wp3);

    // ---- layer 1: Hg = dinv*(XA@W1); XB = relu(agg(Hg))
    k_mfma256<<<BM, 256, 0, stream>>>(XA, Wp1, dinv, Hg);
    k_gather256<1><<<BG, 256, 0, stream>>>(Hg, b1, dinv, rowptr, csr16, nullptr, XB);

    // ---- layer 2: Hg = dinv*(XB@W2); XA = relu(relu(agg(Hg)) + XB)
    k_mfma256<<<BM, 256, 0, stream>>>(XB, Wp2, dinv, Hg);
    k_gather256<2><<<BG, 256, 0, stream>>>(Hg, b2, dinv, rowptr, csr16, XB, XA);

    // ---- layer 3: Hg = dinv*(XA@W3); XB = relu(relu(agg(Hg)) + XA)
    k_mfma256<<<BM, 256, 0, stream>>>(XA, Wp3, dinv, Hg);
    k_gather256<2><<<BG, 256, 0, stream>>>(Hg, b3, dinv, rowptr, csr16, XA, XB);

    // ---- layer 4: G16 = dinv*(XB@W4); fused gather+pool
    k_gemm16<<<BN, 256, 0, stream>>>(XB, W4, dinv, G16);
    k_g16pool<<<B4, 256, 0, stream>>>(G16, b4, dinv, rowptr, csr16, bvec, pool, cnt);

    // ---- finalize
    k_final<<<4, 256, 0, stream>>>(pool, cnt, out);
}

// Round 9
// 439.268 us; speedup vs baseline: 1.1357x; 1.1081x over previous
//
#include <hip/hip_runtime.h>
#include <hip/hip_bf16.h>

#define N_NODES 50000
#define N_EDGES 800000
#define F 256
#define NGRAPH 64
#define NCLS 16
#define NBLK_N 196   // ceil(50000/256)

typedef short short8 __attribute__((ext_vector_type(8)));
typedef float f32x4 __attribute__((ext_vector_type(4)));

__device__ __forceinline__ float bf2f(ushort u) {
    unsigned v = ((unsigned)u) << 16;
    return __uint_as_float(v);
}
__device__ __forceinline__ ushort f2bf(float f) {
    __hip_bfloat16 b = __float2bfloat16(f);   // RNE
    return *reinterpret_cast<ushort*>(&b);
}
__device__ __forceinline__ float bflo(uint u) { return __uint_as_float(u << 16); }
__device__ __forceinline__ float bfhi(uint u) { return __uint_as_float(u & 0xffff0000u); }

// ---------------- CSR build ----------------

__global__ __launch_bounds__(256) void k_zero_int(int* __restrict__ p, int n) {
    int i = blockIdx.x * 256 + threadIdx.x;
    if (i < n) p[i] = 0;
}

__global__ __launch_bounds__(256) void k_count(const int* __restrict__ dst,
                                               int* __restrict__ ecnt) {
    int e = blockIdx.x * 256 + threadIdx.x;
    if (e < N_EDGES) atomicAdd(&ecnt[dst[e]], 1);
}

// block-scan over ecnt; also emits dinv (fused)
__global__ __launch_bounds__(256) void k_scan_block(const int* __restrict__ ecnt,
                                                    int* __restrict__ rowptr,
                                                    int* __restrict__ blkSum,
                                                    float* __restrict__ dinv) {
    __shared__ int sh[256];
    int i = blockIdx.x * 256 + threadIdx.x;
    int v = (i < N_NODES) ? ecnt[i] : 0;
    sh[threadIdx.x] = v;
    __syncthreads();
#pragma unroll
    for (int off = 1; off < 256; off <<= 1) {
        int t = (threadIdx.x >= off) ? sh[threadIdx.x - off] : 0;
        __syncthreads();
        sh[threadIdx.x] += t;
        __syncthreads();
    }
    if (i < N_NODES) {
        rowptr[i] = sh[threadIdx.x] - v;
        dinv[i] = rsqrtf((float)(v + 1));   // +1 self-loop
    }
    if (threadIdx.x == 255) blkSum[blockIdx.x] = sh[255];
}

__global__ __launch_bounds__(256) void k_scan_tops(int* __restrict__ blkSum,
                                                   int* __restrict__ blkOff) {
    __shared__ int sh[256];
    int v = (threadIdx.x < NBLK_N) ? blkSum[threadIdx.x] : 0;
    sh[threadIdx.x] = v;
    __syncthreads();
#pragma unroll
    for (int off = 1; off < 256; off <<= 1) {
        int t = (threadIdx.x >= off) ? sh[threadIdx.x - off] : 0;
        __syncthreads();
        sh[threadIdx.x] += t;
        __syncthreads();
    }
    if (threadIdx.x < NBLK_N) blkOff[threadIdx.x] = sh[threadIdx.x] - v;
}

__global__ __launch_bounds__(256) void k_scan_add(int* __restrict__ rowptr,
                                                  const int* __restrict__ blkOff,
                                                  int* __restrict__ cursor) {
    int i = blockIdx.x * 256 + threadIdx.x;
    if (i < N_NODES) {
        int r = rowptr[i] + blkOff[blockIdx.x];
        rowptr[i] = r;
        cursor[i] = r;
    }
    if (i == 0) rowptr[N_NODES] = N_EDGES;
}

__global__ __launch_bounds__(256) void k_fill_csr(const int* __restrict__ src,
                                                  const int* __restrict__ dst,
                                                  int* __restrict__ cursor,
                                                  ushort* __restrict__ csr16) {
    int e = blockIdx.x * 256 + threadIdx.x;
    if (e >= N_EDGES) return;
    int s = src[e];
    int d = dst[e];
    int p = atomicAdd(&cursor[d], 1);
    csr16[p] = (ushort)s;
}

// ---------------- casts / packs ----------------

__global__ __launch_bounds__(256) void k_cast_bf16(const float* __restrict__ in,
                                                   ushort* __restrict__ out,
                                                   int n8) {
    int i = blockIdx.x * 256 + threadIdx.x;
    if (i >= n8) return;
    const float4* ip = (const float4*)(in + (size_t)i * 8);
    float4 a = ip[0], b = ip[1];
    short8 v;
    v[0] = (short)f2bf(a.x); v[1] = (short)f2bf(a.y);
    v[2] = (short)f2bf(a.z); v[3] = (short)f2bf(a.w);
    v[4] = (short)f2bf(b.x); v[5] = (short)f2bf(b.y);
    v[6] = (short)f2bf(b.z); v[7] = (short)f2bf(b.w);
    *(short8*)(out + (size_t)i * 8) = v;
}

// pack W[256][256] f32 -> fragment order bf16
__global__ __launch_bounds__(256) void k_wpack(const float* __restrict__ W,
                                               ushort* __restrict__ Wp) {
    int idx = blockIdx.x * 256 + threadIdx.x;
    if (idx >= 16 * 8 * 64) return;
    int lane = idx & 63;
    int ks = (idx >> 6) & 7;
    int ctg = idx >> 9;
    int kbase = ks * 32 + (lane >> 4) * 8;
    int col = ctg * 16 + (lane & 15);
    short8 v;
#pragma unroll
    for (int e = 0; e < 8; ++e)
        v[e] = (short)f2bf(W[(size_t)(kbase + e) * 256 + col]);
    *(short8*)(Wp + (size_t)idx * 8) = v;
}

// ---------------- MFMA GEMM (R4/R5 config: wf[4][8] in regs, BM=64) ----------------
// C[r][:] = f2bf( dinv[r] * (A[r][:] @ W) )

__global__ __launch_bounds__(256, 2) void k_mfma256(const ushort* __restrict__ Ab,
                                                    const ushort* __restrict__ Wp,
                                                    const float* __restrict__ dinv,
                                                    ushort* __restrict__ C) {
    const int t = threadIdx.x;
    const int wv = t >> 6;
    const int l = t & 63;
    const int m0 = blockIdx.x * 64;
    const int colbase = wv * 64;
    const int lrow = l & 15;
    const int lk = (l >> 4) * 8;

    short8 wf[4][8];
    const short8* wp = (const short8*)Wp;
#pragma unroll
    for (int ct = 0; ct < 4; ++ct)
#pragma unroll
        for (int ks = 0; ks < 8; ++ks)
            wf[ct][ks] = wp[(size_t)(((wv * 4 + ct) * 8 + ks) * 64) + l];

#pragma unroll
    for (int msub = 0; msub < 4; ++msub) {
        int arow = m0 + msub * 16 + lrow;
        if (arow >= N_NODES) arow = N_NODES - 1;
        const ushort* ap = Ab + (size_t)arow * F + lk;
        short8 af[8];
#pragma unroll
        for (int ks = 0; ks < 8; ++ks)
            af[ks] = *(const short8*)(ap + ks * 32);

        f32x4 acc[4];
#pragma unroll
        for (int ct = 0; ct < 4; ++ct) acc[ct] = (f32x4){0.f, 0.f, 0.f, 0.f};
#pragma unroll
        for (int ks = 0; ks < 8; ++ks)
#pragma unroll
            for (int ct = 0; ct < 4; ++ct)
                acc[ct] = __builtin_amdgcn_mfma_f32_16x16x32_bf16(af[ks], wf[ct][ks], acc[ct], 0, 0, 0);

        int orow0 = m0 + msub * 16 + (l >> 4) * 4;
        float dv[4];
#pragma unroll
        for (int r = 0; r < 4; ++r)
            dv[r] = (orow0 + r < N_NODES) ? dinv[orow0 + r] : 0.f;
#pragma unroll
        for (int ct = 0; ct < 4; ++ct) {
            int ocol = colbase + ct * 16 + (l & 15);
#pragma unroll
            for (int r = 0; r < 4; ++r) {
                int orow = orow0 + r;
                if (orow < N_NODES)
                    C[(size_t)orow * F + ocol] = f2bf(acc[ct][r] * dv[r]);
            }
        }
    }
}

// ---------------- fused gather aggregation, F=256, bf16 in/out ----------------
// 2-slot wave: 32 lanes x 16B cover one 512B row; one VMEM inst = 2 edge rows.
// H dinv-prescaled: out_d = act( bias + dinv_d * (sum_{s in N(d)} H[s] + H[d]) )
// MODE 1: relu(agg)   MODE 2: relu(relu(agg) + hc)

template <int MODE>
__global__ __launch_bounds__(256) void k_gather256(const ushort* __restrict__ H,
                                                   const float* __restrict__ bias,
                                                   const float* __restrict__ dinv,
                                                   const int* __restrict__ rowptr,
                                                   const ushort* __restrict__ csr16,
                                                   const ushort* __restrict__ hc,
                                                   ushort* __restrict__ OUT) {
    int gid = blockIdx.x * 256 + threadIdx.x;
    int n = gid >> 6;
    int lane = gid & 63;
    if (n >= N_NODES) return;
    const int slot = lane >> 5;    // 0..1
    const int c = (lane & 31) * 8; // this lane's 8-feat block

    float acc[8];
#pragma unroll
    for (int j = 0; j < 8; ++j) acc[j] = 0.f;

    int i = rowptr[n] + slot;
    const int end = rowptr[n + 1];
    // 4 edges per slot per iteration (8 edges per wave-iter), 64B in flight/lane
    for (; i + 6 < end; i += 8) {
        int s0 = csr16[i], s1 = csr16[i + 2], s2 = csr16[i + 4], s3 = csr16[i + 6];
        short8 v0 = *(const short8*)(H + (size_t)s0 * F + c);
        short8 v1 = *(const short8*)(H + (size_t)s1 * F + c);
        short8 v2 = *(const short8*)(H + (size_t)s2 * F + c);
        short8 v3 = *(const short8*)(H + (size_t)s3 * F + c);
#pragma unroll
        for (int j = 0; j < 8; ++j)
            acc[j] += (bf2f((ushort)v0[j]) + bf2f((ushort)v1[j])) +
                      (bf2f((ushort)v2[j]) + bf2f((ushort)v3[j]));
    }
    for (; i < end; i += 2) {
        int s0 = csr16[i];
        short8 v0 = *(const short8*)(H + (size_t)s0 * F + c);
#pragma unroll
        for (int j = 0; j < 8; ++j) acc[j] += bf2f((ushort)v0[j]);
    }

    // combine the two slots
#pragma unroll
    for (int j = 0; j < 8; ++j) acc[j] += __shfl_xor(acc[j], 32);

    if (slot == 0) {
        const short8 h = *(const short8*)(H + (size_t)n * F + c);
        const float4 b0 = *(const float4*)(bias + c);
        const float4 b1 = *(const float4*)(bias + c + 4);
        float bb[8] = {b0.x, b0.y, b0.z, b0.w, b1.x, b1.y, b1.z, b1.w};
        float di = dinv[n];
        float s[8];
#pragma unroll
        for (int j = 0; j < 8; ++j)
            s[j] = bb[j] + di * (acc[j] + bf2f((ushort)h[j]));

        short8 ov;
        if (MODE == 1) {
#pragma unroll
            for (int j = 0; j < 8; ++j)
                ov[j] = (short)f2bf(fmaxf(s[j], 0.f));
        } else {
            const short8 hv = *(const short8*)(hc + (size_t)n * F + c);
#pragma unroll
            for (int j = 0; j < 8; ++j)
                ov[j] = (short)f2bf(fmaxf(fmaxf(s[j], 0.f) + bf2f((ushort)hv[j]), 0.f));
        }
        *(short8*)(OUT + (size_t)n * F + c) = ov;
    }
}

// ---------------- layer 4: GEMM 256 -> 16, dinv-prescaled bf16 out ----------------

__global__ __launch_bounds__(256) void k_gemm16(const ushort* __restrict__ A,
                                                const float* __restrict__ W4,
                                                const float* __restrict__ dinv,
                                                ushort* __restrict__ C) {
    __shared__ float Ws[256][16];
    const int t = threadIdx.x;
    {
        const float4* wp = (const float4*)(W4 + (size_t)t * 16);
        float4 a = wp[0], b = wp[1], c = wp[2], d = wp[3];
        float4* sp = (float4*)&Ws[t][0];
        sp[0] = a; sp[1] = b; sp[2] = c; sp[3] = d;
    }
    __syncthreads();
    int row = blockIdx.x * 256 + t;
    if (row >= N_NODES) return;
    const short8* ap = (const short8*)(A + (size_t)row * F);
    float acc[16];
#pragma unroll
    for (int c = 0; c < 16; ++c) acc[c] = 0.f;
    for (int k8 = 0; k8 < 32; ++k8) {
        short8 a8 = ap[k8];
#pragma unroll
        for (int j = 0; j < 8; ++j) {
            float av = bf2f((ushort)a8[j]);
            const float4* wr = (const float4*)&Ws[k8 * 8 + j][0];
            float4 w0 = wr[0], w1 = wr[1], w2 = wr[2], w3 = wr[3];
            acc[0]  += av * w0.x; acc[1]  += av * w0.y;
            acc[2]  += av * w0.z; acc[3]  += av * w0.w;
            acc[4]  += av * w1.x; acc[5]  += av * w1.y;
            acc[6]  += av * w1.z; acc[7]  += av * w1.w;
            acc[8]  += av * w2.x; acc[9]  += av * w2.y;
            acc[10] += av * w2.z; acc[11] += av * w2.w;
            acc[12] += av * w3.x; acc[13] += av * w3.y;
            acc[14] += av * w3.z; acc[15] += av * w3.w;
        }
    }
    float dv = dinv[row];
    short8 o0, o1;
#pragma unroll
    for (int c = 0; c < 8; ++c) o0[c] = (short)f2bf(acc[c] * dv);
#pragma unroll
    for (int c = 0; c < 8; ++c) o1[c] = (short)f2bf(acc[8 + c] * dv);
    short8* op = (short8*)(C + (size_t)row * 16);
    op[0] = o0; op[1] = o1;
}

// ---------------- fused layer-4 gather + mean-pool accumulate ----------------

__global__ __launch_bounds__(256) void k_g16pool(const ushort* __restrict__ G16,
                                                 const float* __restrict__ bias,
                                                 const float* __restrict__ dinv,
                                                 const int* __restrict__ rowptr,
                                                 const ushort* __restrict__ csr16,
                                                 const int* __restrict__ batch,
                                                 float* __restrict__ pool,
                                                 float* __restrict__ cnt) {
    __shared__ float ps[NGRAPH][NCLS];
    __shared__ float pc[NGRAPH];
    for (int i = threadIdx.x; i < NGRAPH * NCLS; i += 256) ((float*)ps)[i] = 0.f;
    if (threadIdx.x < NGRAPH) pc[threadIdx.x] = 0.f;
    __syncthreads();

    int gid = blockIdx.x * 256 + threadIdx.x;
    int n = gid >> 2;
    int q = (gid & 3) * 4;
    if (n < N_NODES) {
        float ax = 0.f, ay = 0.f, az = 0.f, aw = 0.f;
        const int end = rowptr[n + 1];
        for (int i = rowptr[n]; i < end; ++i) {
            int s0 = csr16[i];
            const uint2 u = *(const uint2*)(G16 + (size_t)s0 * 16 + q);
            ax += bflo(u.x); ay += bfhi(u.x);
            az += bflo(u.y); aw += bfhi(u.y);
        }
        const uint2 hu = *(const uint2*)(G16 + (size_t)n * 16 + q);
        const float4 b = *(const float4*)(bias + q);
        float di = dinv[n];
        int g = batch[n];
        atomicAdd(&ps[g][q + 0], b.x + di * (ax + bflo(hu.x)));
        atomicAdd(&ps[g][q + 1], b.y + di * (ay + bfhi(hu.x)));
        atomicAdd(&ps[g][q + 2], b.z + di * (az + bflo(hu.y)));
        atomicAdd(&ps[g][q + 3], b.w + di * (aw + bfhi(hu.y)));
        if ((gid & 3) == 0) atomicAdd(&pc[g], 1.f);
    }
    __syncthreads();

    for (int i = threadIdx.x; i < NGRAPH * NCLS; i += 256) {
        float v = ((float*)ps)[i];
        if (v != 0.f) unsafeAtomicAdd(&pool[i], v);
    }
    if (threadIdx.x < NGRAPH) {
        float v = pc[threadIdx.x];
        if (v > 0.f) unsafeAtomicAdd(&cnt[threadIdx.x], v);
    }
}

__global__ __launch_bounds__(256) void k_pool_zero(float* __restrict__ pool,
                                                   float* __restrict__ cnt) {
    int i = blockIdx.x * 256 + threadIdx.x;
    if (i < NGRAPH * NCLS) pool[i] = 0.f;
    if (i < NGRAPH) cnt[i] = 0.f;
}

__global__ __launch_bounds__(256) void k_final(const float* __restrict__ pool,
                                               const float* __restrict__ cnt,
                                               float* __restrict__ out) {
    int i = blockIdx.x * 256 + threadIdx.x;
    if (i < NGRAPH * NCLS) out[i] = pool[i] / fmaxf(cnt[i >> 4], 1.f);
}

// ---------------- host ----------------

extern "C" void kernel_launch(void* const* d_in, const int* in_sizes, int n_in,
                              void* d_out, int out_size, void* d_ws, size_t ws_size,
                              hipStream_t stream) {
    const float* x   = (const float*)d_in[0];
    const int*   ei  = (const int*)d_in[1];
    const int*   bvec= (const int*)d_in[2];
    const float* W1  = (const float*)d_in[3];
    const float* b1  = (const float*)d_in[4];
    const float* W2  = (const float*)d_in[5];
    const float* b2  = (const float*)d_in[6];
    const float* W3  = (const float*)d_in[7];
    const float* b3  = (const float*)d_in[8];
    const float* W4  = (const float*)d_in[9];
    const float* b4  = (const float*)d_in[10];
    float* out = (float*)d_out;

    const int* src = ei;
    const int* dst = ei + N_EDGES;

    const size_t NF = (size_t)N_NODES * F;            // 12.8M elems
    float* ws = (float*)d_ws;
    ushort* XA = (ushort*)ws;                          // NF bf16
    ushort* XB = XA + NF;                              // NF bf16
    ushort* Hg = XB + NF;                              // NF bf16 (prescaled GEMM out)
    ushort* G16 = (ushort*)(ws + 3 * NF / 2);          // N*16 bf16 (prescaled)
    float*  aux = ws + 3 * NF / 2 + 400000;
    int*    ecnt   = (int*)aux;                        // N
    float*  dinv   = aux + N_NODES;                    // N
    int*    rowptr = (int*)(aux + 2 * N_NODES);        // N+1 (+pad)
    int*    cursor = (int*)(aux + 3 * N_NODES + 64);   // N
    int*    blkSum = (int*)(aux + 4 * N_NODES + 64);   // 256
    int*    blkOff = blkSum + 256;                     // 256
    ushort* csr16  = (ushort*)(blkOff + 256);          // E ushorts
    float*  pool   = (float*)(csr16 + N_EDGES);        // 1024
    float*  cnt    = pool + NGRAPH * NCLS;             // 64
    ushort* Wp1    = (ushort*)(cnt + NGRAPH);          // 65536 each
    ushort* Wp2    = Wp1 + 65536;
    ushort* Wp3    = Wp2 + 65536;

    const int BN = NBLK_N;                        // 196
    const int BE = (N_EDGES + 255) / 256;         // 3125
    const int BM = (N_NODES + 63) / 64;           // 782 MFMA blocks (BM=64)
    const int BG = (N_NODES * 64 + 255) / 256;    // 12500 (wave/node)
    const int B4 = (N_NODES * 4 + 255) / 256;     // 782
    const int BC = (int)((NF / 8 + 255) / 256);   // cast blocks

    // ---- CSR build + dinv
    k_zero_int<<<BN, 256, 0, stream>>>(ecnt, N_NODES);
    k_pool_zero<<<5, 256, 0, stream>>>(pool, cnt);
    k_count<<<BE, 256, 0, stream>>>(dst, ecnt);
    k_scan_block<<<BN, 256, 0, stream>>>(ecnt, rowptr, blkSum, dinv);
    k_scan_tops<<<1, 256, 0, stream>>>(blkSum, blkOff);
    k_scan_add<<<BN, 256, 0, stream>>>(rowptr, blkOff, cursor);
    k_fill_csr<<<BE, 256, 0, stream>>>(src, dst, cursor, csr16);

    // ---- casts & weight packs
    k_cast_bf16<<<BC, 256, 0, stream>>>(x, XA, (int)(NF / 8));
    k_wpack<<<32, 256, 0, stream>>>(W1, Wp1);
    k_wpack<<<32, 256, 0, stream>>>(W2, Wp2);
    k_wpack<<<32, 256, 0, stream>>>(W3, Wp3);

    // ---- layer 1: Hg = dinv*(XA@W1); XB = relu(agg(Hg))
    k_mfma256<<<BM, 256, 0, stream>>>(XA, Wp1, dinv, Hg);
    k_gather256<1><<<BG, 256, 0, stream>>>(Hg, b1, dinv, rowptr, csr16, nullptr, XB);

    // ---- layer 2: Hg = dinv*(XB@W2); XA = relu(relu(agg(Hg)) + XB)
    k_mfma256<<<BM, 256, 0, stream>>>(XB, Wp2, dinv, Hg);
    k_gather256<2><<<BG, 256, 0, stream>>>(Hg, b2, dinv, rowptr, csr16, XB, XA);

    // ---- layer 3: Hg = dinv*(XA@W3); XB = relu(relu(agg(Hg)) + XA)
    k_mfma256<<<BM, 256, 0, stream>>>(XA, Wp3, dinv, Hg);
    k_gather256<2><<<BG, 256, 0, stream>>>(Hg, b3, dinv, rowptr, csr16, XA, XB);

    // ---- layer 4: G16 = dinv*(XB@W4); fused gather+pool
    k_gemm16<<<BN, 256, 0, stream>>>(XB, W4, dinv, G16);
    k_g16pool<<<B4, 256, 0, stream>>>(G16, b4, dinv, rowptr, csr16, bvec, pool, cnt);

    // ---- finalize
    k_final<<<4, 256, 0, stream>>>(pool, cnt, out);
}

// Round 10
// 402.056 us; speedup vs baseline: 1.2408x; 1.0926x over previous
//
#include <hip/hip_runtime.h>
#include <hip/hip_bf16.h>

#define N_NODES 50000
#define N_EDGES 800000
#define F 256
#define NGRAPH 64
#define NCLS 16
#define NBLK_N 196   // ceil(50000/256)

typedef short short8 __attribute__((ext_vector_type(8)));
typedef float f32x4 __attribute__((ext_vector_type(4)));

__device__ __forceinline__ float bf2f(ushort u) {
    unsigned v = ((unsigned)u) << 16;
    return __uint_as_float(v);
}
__device__ __forceinline__ ushort f2bf(float f) {
    __hip_bfloat16 b = __float2bfloat16(f);   // RNE
    return *reinterpret_cast<ushort*>(&b);
}
__device__ __forceinline__ float bflo(uint u) { return __uint_as_float(u << 16); }
__device__ __forceinline__ float bfhi(uint u) { return __uint_as_float(u & 0xffff0000u); }

// ---------------- init (zeroed buffers, fused) ----------------

__global__ __launch_bounds__(256) void k_init(int* __restrict__ ecnt,
                                              float* __restrict__ pool,
                                              float* __restrict__ cnt) {
    int i = blockIdx.x * 256 + threadIdx.x;
    if (i < N_NODES) ecnt[i] = 0;
    if (i < NGRAPH * NCLS) pool[i] = 0.f;
    if (i < NGRAPH) cnt[i] = 0.f;
}

__global__ __launch_bounds__(256) void k_count(const int* __restrict__ dst,
                                               int* __restrict__ ecnt) {
    int e = blockIdx.x * 256 + threadIdx.x;
    if (e < N_EDGES) atomicAdd(&ecnt[dst[e]], 1);
}

// block-scan over ecnt; also emits dinv (fused)
__global__ __launch_bounds__(256) void k_scan_block(const int* __restrict__ ecnt,
                                                    int* __restrict__ rowptr,
                                                    int* __restrict__ blkSum,
                                                    float* __restrict__ dinv) {
    __shared__ int sh[256];
    int i = blockIdx.x * 256 + threadIdx.x;
    int v = (i < N_NODES) ? ecnt[i] : 0;
    sh[threadIdx.x] = v;
    __syncthreads();
#pragma unroll
    for (int off = 1; off < 256; off <<= 1) {
        int t = (threadIdx.x >= off) ? sh[threadIdx.x - off] : 0;
        __syncthreads();
        sh[threadIdx.x] += t;
        __syncthreads();
    }
    if (i < N_NODES) {
        rowptr[i] = sh[threadIdx.x] - v;
        dinv[i] = rsqrtf((float)(v + 1));   // +1 self-loop
    }
    if (threadIdx.x == 255) blkSum[blockIdx.x] = sh[255];
}

// per-block: reduce blkSum[0..bid) inline (replaces scan_tops launch), add.
__global__ __launch_bounds__(256) void k_scan_add(const int* __restrict__ blkSum,
                                                  int* __restrict__ rowptr,
                                                  int* __restrict__ cursor) {
    __shared__ int sh[256];
    int t = threadIdx.x;
    sh[t] = (t < NBLK_N && t < (int)blockIdx.x) ? blkSum[t] : 0;
    __syncthreads();
#pragma unroll
    for (int off = 128; off > 0; off >>= 1) {
        if (t < off) sh[t] += sh[t + off];
        __syncthreads();
    }
    int base = sh[0];
    int i = blockIdx.x * 256 + t;
    if (i < N_NODES) {
        int r = rowptr[i] + base;
        rowptr[i] = r;
        cursor[i] = r;
    }
    if (i == 0) rowptr[N_NODES] = N_EDGES;
}

__global__ __launch_bounds__(256) void k_fill_csr(const int* __restrict__ src,
                                                  const int* __restrict__ dst,
                                                  int* __restrict__ cursor,
                                                  ushort* __restrict__ csr16) {
    int e = blockIdx.x * 256 + threadIdx.x;
    if (e >= N_EDGES) return;
    int s = src[e];
    int d = dst[e];
    int p = atomicAdd(&cursor[d], 1);
    csr16[p] = (ushort)s;
}

// ---------------- weight pack: all three 256x256 in one launch ----------------
// Wp[((ctg*8+ks)*64 + lane)*8 + e] = W[ks*32 + (lane>>4)*8 + e][ctg*16 + (lane&15)]

__global__ __launch_bounds__(256) void k_wpack3(const float* __restrict__ W1,
                                                const float* __restrict__ W2,
                                                const float* __restrict__ W3,
                                                ushort* __restrict__ Wp) {
    int gid = blockIdx.x * 256 + threadIdx.x;
    int which = gid >> 13;          // 8192 frag-groups per matrix
    int idx = gid & 8191;
    const float* W = (which == 0) ? W1 : (which == 1) ? W2 : W3;
    ushort* o = Wp + (size_t)which * 65536;
    int lane = idx & 63;
    int ks = (idx >> 6) & 7;
    int ctg = idx >> 9;
    int kbase = ks * 32 + (lane >> 4) * 8;
    int col = ctg * 16 + (lane & 15);
    short8 v;
#pragma unroll
    for (int e = 0; e < 8; ++e)
        v[e] = (short)f2bf(W[(size_t)(kbase + e) * 256 + col]);
    *(short8*)(o + (size_t)idx * 8) = v;
}

// ---------------- MFMA GEMM, dinv-prescaled bf16 out, LDS-staged C ----------------
// C[r][:] = f2bf( dinv[r] * (A[r][:] @ W) ).  BM=64, wf[4][8] register-resident.
// F32IN=1: A is f32 (layer 1, fuses the x->bf16 cast in-register).
// Epilogue stages each wave's 16x64 tile in private LDS (intra-wave, no barrier)
// then stores 128B-contiguous short8 chunks (full cache lines).

template <int F32IN>
__global__ __launch_bounds__(256, 2) void k_mfma256(const void* __restrict__ Av,
                                                    const ushort* __restrict__ Wp,
                                                    const float* __restrict__ dinv,
                                                    ushort* __restrict__ C) {
    __shared__ __align__(16) ushort cs[4][16 * 64];   // 8 KB, per-wave slices
    const int t = threadIdx.x;
    const int wv = t >> 6;
    const int l = t & 63;
    const int m0 = blockIdx.x * 64;
    const int colbase = wv * 64;
    const int lrow = l & 15;
    const int lk = (l >> 4) * 8;

    short8 wf[4][8];
    const short8* wp = (const short8*)Wp;
#pragma unroll
    for (int ct = 0; ct < 4; ++ct)
#pragma unroll
        for (int ks = 0; ks < 8; ++ks)
            wf[ct][ks] = wp[(size_t)(((wv * 4 + ct) * 8 + ks) * 64) + l];

#pragma unroll
    for (int msub = 0; msub < 4; ++msub) {
        int arow = m0 + msub * 16 + lrow;
        if (arow >= N_NODES) arow = N_NODES - 1;
        short8 af[8];
        if (F32IN) {
            const float* ap = (const float*)Av + (size_t)arow * F + lk;
#pragma unroll
            for (int ks = 0; ks < 8; ++ks) {
                float4 a0 = *(const float4*)(ap + ks * 32);
                float4 a1 = *(const float4*)(ap + ks * 32 + 4);
                af[ks][0] = (short)f2bf(a0.x); af[ks][1] = (short)f2bf(a0.y);
                af[ks][2] = (short)f2bf(a0.z); af[ks][3] = (short)f2bf(a0.w);
                af[ks][4] = (short)f2bf(a1.x); af[ks][5] = (short)f2bf(a1.y);
                af[ks][6] = (short)f2bf(a1.z); af[ks][7] = (short)f2bf(a1.w);
            }
        } else {
            const ushort* ap = (const ushort*)Av + (size_t)arow * F + lk;
#pragma unroll
            for (int ks = 0; ks < 8; ++ks)
                af[ks] = *(const short8*)(ap + ks * 32);
        }

        f32x4 acc[4];
#pragma unroll
        for (int ct = 0; ct < 4; ++ct) acc[ct] = (f32x4){0.f, 0.f, 0.f, 0.f};
#pragma unroll
        for (int ks = 0; ks < 8; ++ks)
#pragma unroll
            for (int ct = 0; ct < 4; ++ct)
                acc[ct] = __builtin_amdgcn_mfma_f32_16x16x32_bf16(af[ks], wf[ct][ks], acc[ct], 0, 0, 0);

        int orow0 = m0 + msub * 16 + (l >> 4) * 4;
        float dv[4];
#pragma unroll
        for (int r = 0; r < 4; ++r)
            dv[r] = (orow0 + r < N_NODES) ? dinv[orow0 + r] : 0.f;

        // stage to this wave's LDS slice (intra-wave exchange, no barrier)
#pragma unroll
        for (int ct = 0; ct < 4; ++ct) {
            int col = ct * 16 + (l & 15);
#pragma unroll
            for (int r = 0; r < 4; ++r) {
                int row = (l >> 4) * 4 + r;
                cs[wv][row * 64 + col] = f2bf(acc[ct][r] * dv[r]);
            }
        }
        // read back row-major, store 128B-contiguous
#pragma unroll
        for (int h = 0; h < 2; ++h) {
            int row = h * 8 + (l >> 3);
            int coff = (l & 7) * 8;
            short8 v = *(const short8*)&cs[wv][row * 64 + coff];
            int orow = m0 + msub * 16 + row;
            if (orow < N_NODES)
                *(short8*)(C + (size_t)orow * F + colbase + coff) = v;
        }
    }
}

// ---------------- fused gather aggregation, F=256, bf16 in/out ----------------
// 2-slot wave: 32 lanes x 16B cover one 512B row; one VMEM inst = 2 edge rows.
// H dinv-prescaled: out_d = act( bias + dinv_d * (sum_{s in N(d)} H[s] + H[d]) )
// MODE 1: relu(agg)   MODE 2: relu(relu(agg) + hc)

template <int MODE>
__global__ __launch_bounds__(256) void k_gather256(const ushort* __restrict__ H,
                                                   const float* __restrict__ bias,
                                                   const float* __restrict__ dinv,
                                                   const int* __restrict__ rowptr,
                                                   const ushort* __restrict__ csr16,
                                                   const ushort* __restrict__ hc,
                                                   ushort* __restrict__ OUT) {
    int gid = blockIdx.x * 256 + threadIdx.x;
    int n = gid >> 6;
    int lane = gid & 63;
    if (n >= N_NODES) return;
    const int slot = lane >> 5;    // 0..1
    const int c = (lane & 31) * 8; // this lane's 8-feat block

    float acc[8];
#pragma unroll
    for (int j = 0; j < 8; ++j) acc[j] = 0.f;

    int i = rowptr[n] + slot;
    const int end = rowptr[n + 1];
    for (; i + 6 < end; i += 8) {
        int s0 = csr16[i], s1 = csr16[i + 2], s2 = csr16[i + 4], s3 = csr16[i + 6];
        short8 v0 = *(const short8*)(H + (size_t)s0 * F + c);
        short8 v1 = *(const short8*)(H + (size_t)s1 * F + c);
        short8 v2 = *(const short8*)(H + (size_t)s2 * F + c);
        short8 v3 = *(const short8*)(H + (size_t)s3 * F + c);
#pragma unroll
        for (int j = 0; j < 8; ++j)
            acc[j] += (bf2f((ushort)v0[j]) + bf2f((ushort)v1[j])) +
                      (bf2f((ushort)v2[j]) + bf2f((ushort)v3[j]));
    }
    for (; i < end; i += 2) {
        int s0 = csr16[i];
        short8 v0 = *(const short8*)(H + (size_t)s0 * F + c);
#pragma unroll
        for (int j = 0; j < 8; ++j) acc[j] += bf2f((ushort)v0[j]);
    }

#pragma unroll
    for (int j = 0; j < 8; ++j) acc[j] += __shfl_xor(acc[j], 32);

    if (slot == 0) {
        const short8 h = *(const short8*)(H + (size_t)n * F + c);
        const float4 b0 = *(const float4*)(bias + c);
        const float4 b1 = *(const float4*)(bias + c + 4);
        float bb[8] = {b0.x, b0.y, b0.z, b0.w, b1.x, b1.y, b1.z, b1.w};
        float di = dinv[n];
        float s[8];
#pragma unroll
        for (int j = 0; j < 8; ++j)
            s[j] = bb[j] + di * (acc[j] + bf2f((ushort)h[j]));

        short8 ov;
        if (MODE == 1) {
#pragma unroll
            for (int j = 0; j < 8; ++j)
                ov[j] = (short)f2bf(fmaxf(s[j], 0.f));
        } else {
            const short8 hv = *(const short8*)(hc + (size_t)n * F + c);
#pragma unroll
            for (int j = 0; j < 8; ++j)
                ov[j] = (short)f2bf(fmaxf(fmaxf(s[j], 0.f) + bf2f((ushort)hv[j]), 0.f));
        }
        *(short8*)(OUT + (size_t)n * F + c) = ov;
    }
}

// ---------------- layer 4: GEMM 256 -> 16, dinv-prescaled bf16 out ----------------

__global__ __launch_bounds__(256) void k_gemm16(const ushort* __restrict__ A,
                                                const float* __restrict__ W4,
                                                const float* __restrict__ dinv,
                                                ushort* __restrict__ C) {
    __shared__ float Ws[256][16];
    const int t = threadIdx.x;
    {
        const float4* wp = (const float4*)(W4 + (size_t)t * 16);
        float4 a = wp[0], b = wp[1], c = wp[2], d = wp[3];
        float4* sp = (float4*)&Ws[t][0];
        sp[0] = a; sp[1] = b; sp[2] = c; sp[3] = d;
    }
    __syncthreads();
    int row = blockIdx.x * 256 + t;
    if (row >= N_NODES) return;
    const short8* ap = (const short8*)(A + (size_t)row * F);
    float acc[16];
#pragma unroll
    for (int c = 0; c < 16; ++c) acc[c] = 0.f;
    for (int k8 = 0; k8 < 32; ++k8) {
        short8 a8 = ap[k8];
#pragma unroll
        for (int j = 0; j < 8; ++j) {
            float av = bf2f((ushort)a8[j]);
            const float4* wr = (const float4*)&Ws[k8 * 8 + j][0];
            float4 w0 = wr[0], w1 = wr[1], w2 = wr[2], w3 = wr[3];
            acc[0]  += av * w0.x; acc[1]  += av * w0.y;
            acc[2]  += av * w0.z; acc[3]  += av * w0.w;
            acc[4]  += av * w1.x; acc[5]  += av * w1.y;
            acc[6]  += av * w1.z; acc[7]  += av * w1.w;
            acc[8]  += av * w2.x; acc[9]  += av * w2.y;
            acc[10] += av * w2.z; acc[11] += av * w2.w;
            acc[12] += av * w3.x; acc[13] += av * w3.y;
            acc[14] += av * w3.z; acc[15] += av * w3.w;
        }
    }
    float dv = dinv[row];
    short8 o0, o1;
#pragma unroll
    for (int c = 0; c < 8; ++c) o0[c] = (short)f2bf(acc[c] * dv);
#pragma unroll
    for (int c = 0; c < 8; ++c) o1[c] = (short)f2bf(acc[8 + c] * dv);
    short8* op = (short8*)(C + (size_t)row * 16);
    op[0] = o0; op[1] = o1;
}

// ---------------- fused layer-4 gather + mean-pool accumulate ----------------

__global__ __launch_bounds__(256) void k_g16pool(const ushort* __restrict__ G16,
                                                 const float* __restrict__ bias,
                                                 const float* __restrict__ dinv,
                                                 const int* __restrict__ rowptr,
                                                 const ushort* __restrict__ csr16,
                                                 const int* __restrict__ batch,
                                                 float* __restrict__ pool,
                                                 float* __restrict__ cnt) {
    __shared__ float ps[NGRAPH][NCLS];
    __shared__ float pc[NGRAPH];
    for (int i = threadIdx.x; i < NGRAPH * NCLS; i += 256) ((float*)ps)[i] = 0.f;
    if (threadIdx.x < NGRAPH) pc[threadIdx.x] = 0.f;
    __syncthreads();

    int gid = blockIdx.x * 256 + threadIdx.x;
    int n = gid >> 2;
    int q = (gid & 3) * 4;
    if (n < N_NODES) {
        float ax = 0.f, ay = 0.f, az = 0.f, aw = 0.f;
        const int end = rowptr[n + 1];
        for (int i = rowptr[n]; i < end; ++i) {
            int s0 = csr16[i];
            const uint2 u = *(const uint2*)(G16 + (size_t)s0 * 16 + q);
            ax += bflo(u.x); ay += bfhi(u.x);
            az += bflo(u.y); aw += bfhi(u.y);
        }
        const uint2 hu = *(const uint2*)(G16 + (size_t)n * 16 + q);
        const float4 b = *(const float4*)(bias + q);
        float di = dinv[n];
        int g = batch[n];
        atomicAdd(&ps[g][q + 0], b.x + di * (ax + bflo(hu.x)));
        atomicAdd(&ps[g][q + 1], b.y + di * (ay + bfhi(hu.x)));
        atomicAdd(&ps[g][q + 2], b.z + di * (az + bflo(hu.y)));
        atomicAdd(&ps[g][q + 3], b.w + di * (aw + bfhi(hu.y)));
        if ((gid & 3) == 0) atomicAdd(&pc[g], 1.f);
    }
    __syncthreads();

    for (int i = threadIdx.x; i < NGRAPH * NCLS; i += 256) {
        float v = ((float*)ps)[i];
        if (v != 0.f) unsafeAtomicAdd(&pool[i], v);
    }
    if (threadIdx.x < NGRAPH) {
        float v = pc[threadIdx.x];
        if (v > 0.f) unsafeAtomicAdd(&cnt[threadIdx.x], v);
    }
}

__global__ __launch_bounds__(256) void k_final(const float* __restrict__ pool,
                                               const float* __restrict__ cnt,
                                               float* __restrict__ out) {
    int i = blockIdx.x * 256 + threadIdx.x;
    if (i < NGRAPH * NCLS) out[i] = pool[i] / fmaxf(cnt[i >> 4], 1.f);
}

// ---------------- host ----------------

extern "C" void kernel_launch(void* const* d_in, const int* in_sizes, int n_in,
                              void* d_out, int out_size, void* d_ws, size_t ws_size,
                              hipStream_t stream) {
    const float* x   = (const float*)d_in[0];
    const int*   ei  = (const int*)d_in[1];
    const int*   bvec= (const int*)d_in[2];
    const float* W1  = (const float*)d_in[3];
    const float* b1  = (const float*)d_in[4];
    const float* W2  = (const float*)d_in[5];
    const float* b2  = (const float*)d_in[6];
    const float* W3  = (const float*)d_in[7];
    const float* b3  = (const float*)d_in[8];
    const float* W4  = (const float*)d_in[9];
    const float* b4  = (const float*)d_in[10];
    float* out = (float*)d_out;

    const int* src = ei;
    const int* dst = ei + N_EDGES;

    const size_t NF = (size_t)N_NODES * F;            // 12.8M elems
    ushort* P   = (ushort*)d_ws;                       // NF bf16
    ushort* Q   = P + NF;                              // NF bf16
    ushort* Hg  = Q + NF;                              // NF bf16 (prescaled GEMM out)
    ushort* G16 = Hg + NF;                             // N*16 bf16 (prescaled)
    float*  aux = (float*)(G16 + (size_t)N_NODES * 16 + 64);
    int*    ecnt   = (int*)aux;                        // N
    float*  dinv   = aux + N_NODES;                    // N
    int*    rowptr = (int*)(aux + 2 * N_NODES);        // N+1 (+pad)
    int*    cursor = (int*)(aux + 3 * N_NODES + 64);   // N
    int*    blkSum = (int*)(aux + 4 * N_NODES + 64);   // 256
    ushort* csr16  = (ushort*)(blkSum + 256);          // E ushorts
    float*  pool   = (float*)(csr16 + N_EDGES);        // 1024
    float*  cnt    = pool + NGRAPH * NCLS;             // 64
    ushort* Wp     = (ushort*)(cnt + NGRAPH);          // 3 x 65536

    const int BN = NBLK_N;                        // 196
    const int BE = (N_EDGES + 255) / 256;         // 3125
    const int BM = (N_NODES + 63) / 64;           // 782 MFMA blocks (BM=64)
    const int BG = (N_NODES * 64 + 255) / 256;    // 12500 (wave/node)
    const int B4 = (N_NODES * 4 + 255) / 256;     // 782

    // ---- CSR build + dinv + zero-init
    k_init<<<BN, 256, 0, stream>>>(ecnt, pool, cnt);
    k_count<<<BE, 256, 0, stream>>>(dst, ecnt);
    k_scan_block<<<BN, 256, 0, stream>>>(ecnt, rowptr, blkSum, dinv);
    k_scan_add<<<BN, 256, 0, stream>>>(blkSum, rowptr, cursor);
    k_fill_csr<<<BE, 256, 0, stream>>>(src, dst, cursor, csr16);

    // ---- weight packs (single launch)
    k_wpack3<<<96, 256, 0, stream>>>(W1, W2, W3, Wp);

    // ---- layer 1 (cast fused into GEMM): Hg = dinv*(x@W1); P = relu(agg(Hg))
    k_mfma256<1><<<BM, 256, 0, stream>>>(x, Wp, dinv, Hg);
    k_gather256<1><<<BG, 256, 0, stream>>>(Hg, b1, dinv, rowptr, csr16, nullptr, P);

    // ---- layer 2: Hg = dinv*(P@W2); Q = relu(relu(agg(Hg)) + P)
    k_mfma256<0><<<BM, 256, 0, stream>>>(P, Wp + 65536, dinv, Hg);
    k_gather256<2><<<BG, 256, 0, stream>>>(Hg, b2, dinv, rowptr, csr16, P, Q);

    // ---- layer 3: Hg = dinv*(Q@W3); P = relu(relu(agg(Hg)) + Q)
    k_mfma256<0><<<BM, 256, 0, stream>>>(Q, Wp + 131072, dinv, Hg);
    k_gather256<2><<<BG, 256, 0, stream>>>(Hg, b3, dinv, rowptr, csr16, Q, P);

    // ---- layer 4: G16 = dinv*(P@W4); fused gather+pool
    k_gemm16<<<BN, 256, 0, stream>>>(P, W4, dinv, G16);
    k_g16pool<<<B4, 256, 0, stream>>>(G16, b4, dinv, rowptr, csr16, bvec, pool, cnt);

    // ---- finalize
    k_final<<<4, 256, 0, stream>>>(pool, cnt, out);
}